// Round 1
// baseline (240.145 us; speedup 1.0000x reference)
//
#include <hip/hip_runtime.h>
#include <math.h>

#define LL 512
#define EE 1024
#define HH 16
#define DD 64
#define NSX 16               // N*S
#define NT (NSX*LL)          // 8192 tokens
#define NSLE (NT*EE)         // 8388608
// q is pre-scaled by (1/sqrt(512)) * log2(e) so softmax uses native exp2
#define SCALE_Q 0.06375871f

typedef unsigned short u16;
typedef unsigned int u32t;
typedef short bf16x8 __attribute__((ext_vector_type(8)));
typedef float f32x4 __attribute__((ext_vector_type(4)));

__device__ inline u16 f2bf(float f) {
  unsigned u = __float_as_uint(f);
  u += 0x7fff + ((u >> 16) & 1);          // RNE
  return (u16)(u >> 16);
}

// direct builtin calls only; ONLY gfx950-verified MFMA shapes (16x16x32)
#define FEXP2(x) __builtin_amdgcn_exp2f(x)
#define MFMA32(a, b, c) __builtin_amdgcn_mfma_f32_16x16x32_bf16((a), (b), (c), 0, 0, 0)

// async 16B global->LDS (wave-uniform LDS base + lane*16 layout)
__device__ inline void gload16(const void* g, void* l) {
  __builtin_amdgcn_global_load_lds(
      (const __attribute__((address_space(1))) unsigned int*)g,
      (__attribute__((address_space(3))) unsigned int*)l, 16, 0, 0);
}

// ---------------- K0: convert weights fp32 -> bf16 ----------------
__global__ void __launch_bounds__(256) convw_kernel(
    const float* __restrict__ Wv, const float* __restrict__ Wk,
    const float* __restrict__ Wq, const float* __restrict__ Wo,
    u16* __restrict__ Wvb, u16* __restrict__ Wkb,
    u16* __restrict__ Wqb, u16* __restrict__ Wob) {
  int i = blockIdx.x * 256 + threadIdx.x;   // quad index
  const float* s; u16* d; int j;
  if (i < 262144) { s = Wo; d = Wob; j = i; }
  else {
    j = i - 262144;
    if (j < 1024)      { s = Wv; d = Wvb; }
    else if (j < 2048) { s = Wk; d = Wkb; j -= 1024; }
    else               { s = Wq; d = Wqb; j -= 2048; }
  }
  float4 f = ((const float4*)s)[j];
  ushort4 o; o.x = f2bf(f.x); o.y = f2bf(f.y); o.z = f2bf(f.z); o.w = f2bf(f.w);
  ((ushort4*)d)[j] = o;
}

// ---------------- K1: projections via MFMA, LDS-free, pipelined ----------
// grid = mat(3) x ns(16) x hg(4) x tt0(16) = 3072 blocks (2x the old grid for
// latency hiding); wave = one head; each wave processes 2 token-tiles
// (tt = tt0 + 16j) with the NEXT tile's X loads issued before the current
// tile's convert/MFMA/store.
// v stored transposed vpT[ns][h][d][l]; k/q C-layout scatter.
__global__ void __launch_bounds__(256) proj_kernel(
    const float* __restrict__ vals, const float* __restrict__ keys,
    const float* __restrict__ qry,
    const u16* __restrict__ Wvb, const u16* __restrict__ Wkb,
    const u16* __restrict__ Wqb,
    u16* __restrict__ vpT, u16* __restrict__ kp, u16* __restrict__ qp) {
  const int b = blockIdx.x;
  const int tt0 = b & 15, hg = (b >> 4) & 3, ns = (b >> 6) & 15, mat = b >> 10;
  const int tid = threadIdx.x;
  const int wid = tid >> 6, lane = tid & 63, quad = lane >> 4, l16 = lane & 15;
  const int h = hg*4 + wid;
  const float* src = (mat == 0 ? vals : mat == 1 ? keys : qry);
  const u16*   W   = (mat == 0 ? Wvb  : mat == 1 ? Wkb  : Wqb);
  u16* dst = (mat == 1 ? kp : qp);
  const float sc = (mat == 2) ? SCALE_Q : 1.f;
  // ---- W fragments: loaded once, register-resident across both tiles ----
  bf16x8 wf[4][2];
  #pragma unroll
  for (int nt = 0; nt < 4; ++nt) {
    wf[nt][0] = *(const bf16x8*)&W[(nt*16 + l16)*DD + quad*8];
    wf[nt][1] = *(const bf16x8*)&W[(nt*16 + l16)*DD + 32 + quad*8];
  }
  f32x4 z = {0.f, 0.f, 0.f, 0.f};
  // ---- prologue: loads for tile j=0 ----
  const float* xrow0 = src + (size_t)(ns*LL + tt0*16 + l16)*EE + h*DD;
  float4 x0 = *(const float4*)&xrow0[quad*8];
  float4 x1 = *(const float4*)&xrow0[quad*8 + 4];
  float4 x2 = *(const float4*)&xrow0[32 + quad*8];
  float4 x3 = *(const float4*)&xrow0[32 + quad*8 + 4];
  #pragma unroll
  for (int j = 0; j < 2; ++j) {
    const int tt = tt0 + 16*j;
    const int t0 = ns*LL + tt*16;
    // ---- issue NEXT tile's loads before touching this tile's data ----
    float4 n0, n1, n2, n3;
    if (j < 1) {
      const float* xrown = src + (size_t)(t0 + 256 + l16)*EE + h*DD;
      n0 = *(const float4*)&xrown[quad*8];
      n1 = *(const float4*)&xrown[quad*8 + 4];
      n2 = *(const float4*)&xrown[32 + quad*8];
      n3 = *(const float4*)&xrown[32 + quad*8 + 4];
    }
    // ---- convert current tile ----
    bf16x8 af0, af1;
    af0[0] = (short)f2bf(x0.x); af0[1] = (short)f2bf(x0.y);
    af0[2] = (short)f2bf(x0.z); af0[3] = (short)f2bf(x0.w);
    af0[4] = (short)f2bf(x1.x); af0[5] = (short)f2bf(x1.y);
    af0[6] = (short)f2bf(x1.z); af0[7] = (short)f2bf(x1.w);
    af1[0] = (short)f2bf(x2.x); af1[1] = (short)f2bf(x2.y);
    af1[2] = (short)f2bf(x2.z); af1[3] = (short)f2bf(x2.w);
    af1[4] = (short)f2bf(x3.x); af1[5] = (short)f2bf(x3.y);
    af1[6] = (short)f2bf(x3.z); af1[7] = (short)f2bf(x3.w);
    f32x4 acc[4];
    #pragma unroll
    for (int nt = 0; nt < 4; ++nt) {
      acc[nt] = MFMA32(af0, wf[nt][0], z);
      acc[nt] = MFMA32(af1, wf[nt][1], acc[nt]);
    }
    if (mat == 0) {
      // transposed store: rows d = nt*16+l16, 4 consecutive tokens as ushort4
      #pragma unroll
      for (int nt = 0; nt < 4; ++nt) {
        ushort4 o;
        o.x = f2bf(acc[nt][0]); o.y = f2bf(acc[nt][1]);
        o.z = f2bf(acc[nt][2]); o.w = f2bf(acc[nt][3]);
        size_t idx = ((size_t)((ns*HH + h)*DD + nt*16 + l16))*LL + tt*16 + quad*4;
        *(ushort4*)&vpT[idx] = o;
      }
    } else {
      // C-layout scatter: row token = t0+quad*4+r, col = h*64+nt*16+l16
      #pragma unroll
      for (int nt = 0; nt < 4; ++nt)
        #pragma unroll
        for (int r = 0; r < 4; ++r)
          dst[(size_t)(t0 + quad*4 + r)*EE + h*DD + nt*16 + l16] =
              f2bf(acc[nt][r] * sc);
    }
    x0 = n0; x1 = n1; x2 = n2; x3 = n3;
  }
}

// ---------------- K2: fused column-softmax + attention-out ----------------
// one block per (ns,h): 256 blocks x 1024 threads. K resident in LDS; V chunk
// double-buffered. softmax is over the QUERY axis: csum_l = sum_q m_q*exp2(e).
// Phase B uses SWAPPED QK^T (E^T = MFMA(K,Q)) so each lane holds 4 l-values of
// one q-column; P^T reaches the PV B-operand via 8 ds_bpermute + cndmask on
// packed bf16 pairs (no pt LDS buffer, no b16 scatter writes, no pa reads).
// PV computes out^T = V^T * P^T (vb is the A operand, same LDS reads).
__global__ void __launch_bounds__(1024, 4) attn_kernel(
    const u16* __restrict__ qp, const u16* __restrict__ kp,
    const u16* __restrict__ vpT, const int* __restrict__ mask,
    u16* __restrict__ oat) {
  const int b = blockIdx.x;
  const int h = b & 15, ns = b >> 4;
  const int tid = threadIdx.x;
  const int wid = tid >> 6, lane = tid & 63, quad = lane >> 4, l16 = lane & 15;
  __shared__ u16 Ks[LL][72];        // K[l][d]      73728 B
  __shared__ u16 Vt[2][DD][72];     // V^T[d][l64]  18432 B
  __shared__ float psum[16][512];   // phase A partials 32768 B
  __shared__ float csum[LL];        //               2048 B  => 126976 B total
  // ---- stage K ----
  const size_t kgbase = ((size_t)(ns*LL))*EE + h*DD;
  for (int i = tid; i < 4096; i += 1024) {          // 512 rows x 8 segs of 16B
    int row = i >> 3, seg = (i & 7) * 8;
    *(bf16x8*)&Ks[row][seg] = *(const bf16x8*)&kp[kgbase + (size_t)row*EE + seg];
  }
  // ---- persistent Q fragments (wave owns 32 q rows) + masks ----
  const int q0 = wid*32;
  bf16x8 qf[2][2];
  float maf[2][4];    // phase A: q = q0+qt*16+quad*4+r
  float mqf[2];       // phase B: q = q0+qt*16+l16
  #pragma unroll
  for (int qt = 0; qt < 2; ++qt) {
    const u16* qrow = qp + ((size_t)(ns*LL + q0 + qt*16 + l16))*EE + h*DD;
    qf[qt][0] = *(const bf16x8*)&qrow[quad*8];
    qf[qt][1] = *(const bf16x8*)&qrow[32 + quad*8];
    #pragma unroll
    for (int r = 0; r < 4; ++r)
      maf[qt][r] = mask[ns*LL + q0 + qt*16 + quad*4 + r] ? 1.f : 0.f;
    mqf[qt] = mask[ns*LL + q0 + qt*16 + l16] ? 1.f : 0.f;
  }
  f32x4 z = {0.f, 0.f, 0.f, 0.f};
  __syncthreads();
  // ---- phase A: column partial sums -> psum[wid][l], then block reduce ----
  for (int lt = 0; lt < 32; ++lt) {
    bf16x8 kf0 = *(const bf16x8*)&Ks[lt*16 + l16][quad*8];
    bf16x8 kf1 = *(const bf16x8*)&Ks[lt*16 + l16][32 + quad*8];
    float part = 0.f;
    #pragma unroll
    for (int qt = 0; qt < 2; ++qt) {
      f32x4 e = MFMA32(qf[qt][0], kf0, z);
      e = MFMA32(qf[qt][1], kf1, e);
      #pragma unroll
      for (int r = 0; r < 4; ++r)
        part += maf[qt][r] * FEXP2(e[r]);     // e row = q(quad*4+r), col = l(l16)
    }
    part += __shfl_xor(part, 16);             // combine 4 quads (same l16)
    part += __shfl_xor(part, 32);
    if (quad == 0) psum[wid][lt*16 + l16] = part;
  }
  __syncthreads();
  if (tid < LL) {
    float s = 0.f;
    #pragma unroll
    for (int w = 0; w < 16; ++w) s += psum[w][tid];
    csum[tid] = (s > 0.f) ? 1.f/s : 0.f;
  }
  __syncthreads();
  // ---- phase B: swapped E^T -> P^T via shfl -> out^T = V^T * P^T ----
  f32x4 acc[4][2] = {{z,z},{z,z},{z,z},{z,z}};   // [dtile][qt], out^T layout
  const size_t vgbase = ((size_t)((ns*HH + h)*DD))*LL;
  for (int lc = 0; lc < 8; ++lc) {               // 8 chunks of 64 l
    if (tid < 512) {                             // stage V^T[d][lc*64..+63]
      int row = tid >> 3, seg = (tid & 7) * 8;
      *(bf16x8*)&Vt[lc & 1][row][seg] =
          *(const bf16x8*)&vpT[vgbase + (size_t)row*LL + lc*64 + seg];
    }
    __syncthreads();                             // one barrier per chunk (dbuf)
    #pragma unroll
    for (int hf = 0; hf < 2; ++hf) {             // 2 halves of 32 l
      const int lb = lc*64 + hf*32;
      // E^T for two 16-l tiles: lane holds l = t-tile row quad*4+r, q = l16.
      // P packed as bf16 pairs (rows r,r+1): pu[qt][t][pair].
      u32t pu[2][2][2];
      #pragma unroll
      for (int t = 0; t < 2; ++t) {
        const int lrow = lb + t*16 + l16;
        bf16x8 kf0 = *(const bf16x8*)&Ks[lrow][quad*8];
        bf16x8 kf1 = *(const bf16x8*)&Ks[lrow][32 + quad*8];
        float4 cs4 = *(const float4*)&csum[lb + t*16 + quad*4];
        #pragma unroll
        for (int qt = 0; qt < 2; ++qt) {
          f32x4 e = MFMA32(kf0, qf[qt][0], z);
          e = MFMA32(kf1, qf[qt][1], e);
          const float m = mqf[qt];
          u32t p0 = f2bf(FEXP2(e[0]) * (cs4.x * m));
          u32t p1 = f2bf(FEXP2(e[1]) * (cs4.y * m));
          u32t p2 = f2bf(FEXP2(e[2]) * (cs4.z * m));
          u32t p3 = f2bf(FEXP2(e[3]) * (cs4.w * m));
          pu[qt][t][0] = p0 | (p1 << 16);
          pu[qt][t][1] = p2 | (p3 << 16);
        }
      }
      // V^T fragments (A operand): row d = dt*16+l16, k = l = hf*32+quad*8+j
      bf16x8 vb[4];
      #pragma unroll
      for (int dt = 0; dt < 4; ++dt)
        vb[dt] = *(const bf16x8*)&Vt[lc & 1][dt*16 + l16][hf*32 + quad*8];
      // B-frag slot (quad,j) needs P^T[l = quad*8+j][q = l16]:
      //   tile = quad>>1, src lane = ((quad&1)*2 + (j>>2))*16 + l16, reg = j&3
      const int srcLo = (quad & 1)*32 + l16;
      const int srcHi = srcLo + 16;
      const bool hiq = quad >= 2;
      #pragma unroll
      for (int qt = 0; qt < 2; ++qt) {
        u32t a0 = (u32t)__shfl((int)pu[qt][0][0], srcLo);
        u32t a1 = (u32t)__shfl((int)pu[qt][0][1], srcLo);
        u32t a2 = (u32t)__shfl((int)pu[qt][0][0], srcHi);
        u32t a3 = (u32t)__shfl((int)pu[qt][0][1], srcHi);
        u32t b0 = (u32t)__shfl((int)pu[qt][1][0], srcLo);
        u32t b1 = (u32t)__shfl((int)pu[qt][1][1], srcLo);
        u32t b2 = (u32t)__shfl((int)pu[qt][1][0], srcHi);
        u32t b3 = (u32t)__shfl((int)pu[qt][1][1], srcHi);
        union { u32t u[4]; bf16x8 v; } pb;
        pb.u[0] = hiq ? b0 : a0;
        pb.u[1] = hiq ? b1 : a1;
        pb.u[2] = hiq ? b2 : a2;
        pb.u[3] = hiq ? b3 : a3;
        #pragma unroll
        for (int dt = 0; dt < 4; ++dt)
          acc[dt][qt] = MFMA32(vb[dt], pb.v, acc[dt][qt]);
      }
    }
  }
  // ---- write out^T: lane has d = dt*16+quad*4+r, q = qt*16+l16 -> ushort4 ----
  #pragma unroll
  for (int qt = 0; qt < 2; ++qt) {
    const size_t obase = ((size_t)(ns*LL + q0 + qt*16 + l16))*EE + h*DD;
    #pragma unroll
    for (int dt = 0; dt < 4; ++dt) {
      ushort4 o;
      o.x = f2bf(acc[dt][qt][0]); o.y = f2bf(acc[dt][qt][1]);
      o.z = f2bf(acc[dt][qt][2]); o.w = f2bf(acc[dt][qt][3]);
      *(ushort4*)&oat[obase + dt*16 + quad*4] = o;
    }
  }
}

// ---------------- K4: Y = oat @ Wo^T + bo, m97-style MFMA GEMM --------------
// 128x128 tile, BK=64, 4 waves each computing a 64x64 quadrant. Staging via
// global_load_lds width=16 into linear (unpadded) LDS.
__global__ void __launch_bounds__(256) out_gemm_kernel(
    const u16* __restrict__ A, const u16* __restrict__ Wob,
    const float* __restrict__ bo, float* __restrict__ Y) {
  __shared__ u16 As[128][64];   // [m][k]  16384 B, linear for global_load_lds
  __shared__ u16 Bs[128][64];   // [n][k]  16384 B
  const int b = blockIdx.x;     // 64 mtiles x 8 ntiles
  const int nb = b & 7, mb = b >> 3;
  const int m0 = mb*128, n0 = nb*128;
  const int tid = threadIdx.x;
  const int wid = tid >> 6, lane = tid & 63, quad = lane >> 4, l16 = lane & 15;
  const int wm = (wid >> 1)*64, wn = (wid & 1)*64;   // wave quadrant
  const int r0 = tid >> 3, sseg = (tid & 7) * 8;     // staging row/col (u16)
  u16* adst = &As[0][0] + tid*8;                     // lane-linear 16B chunks
  u16* bdst = &Bs[0][0] + tid*8;
  f32x4 z = {0.f, 0.f, 0.f, 0.f};
  f32x4 acc[4][4];
  #pragma unroll
  for (int i = 0; i < 4; ++i)
    #pragma unroll
    for (int j = 0; j < 4; ++j) acc[i][j] = z;
  for (int k0 = 0; k0 < EE; k0 += 64) {
    __syncthreads();                    // previous tile fully consumed
    #pragma unroll
    for (int it = 0; it < 4; ++it) {    // 128 rows x 64 k each, 16B/lane/issue
      gload16(&A  [(size_t)(m0 + it*32 + r0)*EE + k0 + sseg], adst + it*2048);
      gload16(&Wob[(size_t)(n0 + it*32 + r0)*EE + k0 + sseg], bdst + it*2048);
    }
    __syncthreads();                    // vmcnt(0) drain -> LDS data ready
    #pragma unroll
    for (int kk = 0; kk < 2; ++kk) {
      bf16x8 af[4], bfr[4];
      #pragma unroll
      for (int i = 0; i < 4; ++i)
        af[i] = *(const bf16x8*)&As[wm + i*16 + l16][kk*32 + quad*8];
      #pragma unroll
      for (int j = 0; j < 4; ++j)
        bfr[j] = *(const bf16x8*)&Bs[wn + j*16 + l16][kk*32 + quad*8];
      #pragma unroll
      for (int i = 0; i < 4; ++i)
        #pragma unroll
        for (int j = 0; j < 4; ++j)
          acc[i][j] = MFMA32(af[i], bfr[j], acc[i][j]);
    }
  }
  #pragma unroll
  for (int i = 0; i < 4; ++i)
    #pragma unroll
    for (int j = 0; j < 4; ++j) {
      int col = n0 + wn + j*16 + l16;
      float bias = bo[col];
      #pragma unroll
      for (int r = 0; r < 4; ++r)
        Y[(size_t)(m0 + wm + i*16 + quad*4 + r)*EE + col] = acc[i][j][r] + bias;
    }
}

extern "C" void kernel_launch(void* const* d_in, const int* in_sizes, int n_in,
                              void* d_out, int out_size, void* d_ws, size_t ws_size,
                              hipStream_t stream) {
  const float* values = (const float*)d_in[0];
  const float* keysp  = (const float*)d_in[1];
  const float* query  = (const float*)d_in[2];
  const int*   mask   = (const int*)d_in[3];
  const float* Wv = (const float*)d_in[4];
  const float* Wk = (const float*)d_in[5];
  const float* Wq = (const float*)d_in[6];
  const float* Wo = (const float*)d_in[7];
  const float* bo = (const float*)d_in[8];
  float* Y = (float*)d_out;

  u16* qp  = (u16*)d_ws;
  u16* kp  = qp + NSLE;
  u16* vpT = kp + NSLE;
  u16* oat = vpT + NSLE;
  u16* Wob = oat + NSLE;
  u16* Wvb = Wob + EE*EE;
  u16* Wkb = Wvb + DD*DD;
  u16* Wqb = Wkb + DD*DD;

  convw_kernel<<<1036, 256, 0, stream>>>(Wv, Wk, Wq, Wo, Wvb, Wkb, Wqb, Wob);
  proj_kernel<<<3*NSX*4*16, 256, 0, stream>>>(values, keysp, query,
                                              Wvb, Wkb, Wqb, vpT, kp, qp);
  attn_kernel<<<NSX*HH, 1024, 0, stream>>>(qp, kp, vpT, mask, oat);
  out_gemm_kernel<<<(NT/128)*(EE/128), 256, 0, stream>>>(oat, Wob, bo, Y);
}

// Round 2
// 232.845 us; speedup vs baseline: 1.0314x; 1.0314x over previous
//
#include <hip/hip_runtime.h>
#include <math.h>

#define LL 512
#define EE 1024
#define HH 16
#define DD 64
#define NSX 16               // N*S
#define NT (NSX*LL)          // 8192 tokens
#define NSLE (NT*EE)         // 8388608
// q is pre-scaled by (1/sqrt(512)) * log2(e) so softmax uses native exp2
#define SCALE_Q 0.06375871f

typedef unsigned short u16;
typedef short bf16x8 __attribute__((ext_vector_type(8)));
typedef float f32x4 __attribute__((ext_vector_type(4)));

__device__ inline u16 f2bf(float f) {
  unsigned u = __float_as_uint(f);
  u += 0x7fff + ((u >> 16) & 1);          // RNE
  return (u16)(u >> 16);
}

// direct builtin calls only; ONLY gfx950-verified MFMA shapes (16x16x32)
#define FEXP2(x) __builtin_amdgcn_exp2f(x)
#define MFMA32(a, b, c) __builtin_amdgcn_mfma_f32_16x16x32_bf16((a), (b), (c), 0, 0, 0)

// async 16B global->LDS (wave-uniform LDS base + lane*16 layout)
__device__ inline void gload16(const void* g, void* l) {
  __builtin_amdgcn_global_load_lds(
      (const __attribute__((address_space(1))) unsigned int*)g,
      (__attribute__((address_space(3))) unsigned int*)l, 16, 0, 0);
}

// ---------------- K0: convert weights fp32 -> bf16 ----------------
__global__ void __launch_bounds__(256) convw_kernel(
    const float* __restrict__ Wv, const float* __restrict__ Wk,
    const float* __restrict__ Wq, const float* __restrict__ Wo,
    u16* __restrict__ Wvb, u16* __restrict__ Wkb,
    u16* __restrict__ Wqb, u16* __restrict__ Wob) {
  int i = blockIdx.x * 256 + threadIdx.x;   // quad index
  const float* s; u16* d; int j;
  if (i < 262144) { s = Wo; d = Wob; j = i; }
  else {
    j = i - 262144;
    if (j < 1024)      { s = Wv; d = Wvb; }
    else if (j < 2048) { s = Wk; d = Wkb; j -= 1024; }
    else               { s = Wq; d = Wqb; j -= 2048; }
  }
  float4 f = ((const float4*)s)[j];
  ushort4 o; o.x = f2bf(f.x); o.y = f2bf(f.y); o.z = f2bf(f.z); o.w = f2bf(f.w);
  ((ushort4*)d)[j] = o;
}

// ---------------- K1: projections via MFMA, LDS-free, 2-deep pipelined ------
// grid = mat(3) x ns(16) x hg(4) x tt0(8) = 1536 blocks; wave = one head; each
// wave processes 4 token-tiles (tt = tt0 + 8j) with loads for tiles j+1 AND
// j+2 in flight while computing tile j (8 x 16B outstanding -> 2x MLP vs r0).
// v stored transposed vpT[ns][h][d][l] via MFMA(af,wf); k/q stored row-major
// via SWAPPED MFMA(wf,af) (operand-swap layout verified by round-1 pass) so
// the epilogue is 4 ushort4 stores instead of 16 scalar b16.
__global__ void __launch_bounds__(256) proj_kernel(
    const float* __restrict__ vals, const float* __restrict__ keys,
    const float* __restrict__ qry,
    const u16* __restrict__ Wvb, const u16* __restrict__ Wkb,
    const u16* __restrict__ Wqb,
    u16* __restrict__ vpT, u16* __restrict__ kp, u16* __restrict__ qp) {
  const int b = blockIdx.x;
  const int tt0 = b & 7, hg = (b >> 3) & 3, ns = (b >> 5) & 15, mat = b >> 9;
  const int tid = threadIdx.x;
  const int wid = tid >> 6, lane = tid & 63, quad = lane >> 4, l16 = lane & 15;
  const int h = hg*4 + wid;
  const float* src = (mat == 0 ? vals : mat == 1 ? keys : qry);
  const u16*   W   = (mat == 0 ? Wvb  : mat == 1 ? Wkb  : Wqb);
  u16* dst = (mat == 1 ? kp : qp);
  const float sc = (mat == 2) ? SCALE_Q : 1.f;
  // ---- W fragments: loaded once, register-resident across all 4 tiles ----
  bf16x8 wf[4][2];
  #pragma unroll
  for (int nt = 0; nt < 4; ++nt) {
    wf[nt][0] = *(const bf16x8*)&W[(nt*16 + l16)*DD + quad*8];
    wf[nt][1] = *(const bf16x8*)&W[(nt*16 + l16)*DD + 32 + quad*8];
  }
  f32x4 z = {0.f, 0.f, 0.f, 0.f};
  // ---- prologue: loads for tiles j=0 and j=1 ----
  const float* xr0 = src + (size_t)(ns*LL + tt0*16 + l16)*EE + h*DD;
  const float* xr1 = xr0 + (size_t)128*EE;             // +8 token-tiles
  float4 x0 = *(const float4*)&xr0[quad*8];
  float4 x1 = *(const float4*)&xr0[quad*8 + 4];
  float4 x2 = *(const float4*)&xr0[32 + quad*8];
  float4 x3 = *(const float4*)&xr0[32 + quad*8 + 4];
  float4 y0 = *(const float4*)&xr1[quad*8];
  float4 y1 = *(const float4*)&xr1[quad*8 + 4];
  float4 y2 = *(const float4*)&xr1[32 + quad*8];
  float4 y3 = *(const float4*)&xr1[32 + quad*8 + 4];
  #pragma unroll
  for (int j = 0; j < 4; ++j) {
    const int tt = tt0 + 8*j;
    const int t0 = ns*LL + tt*16;
    // ---- issue loads for tile j+2 before touching this tile's data ----
    float4 n0, n1, n2, n3;
    if (j < 2) {
      const float* xrn = src + (size_t)(t0 + 256 + l16)*EE + h*DD;  // +16 tiles
      n0 = *(const float4*)&xrn[quad*8];
      n1 = *(const float4*)&xrn[quad*8 + 4];
      n2 = *(const float4*)&xrn[32 + quad*8];
      n3 = *(const float4*)&xrn[32 + quad*8 + 4];
    }
    // ---- convert current tile ----
    bf16x8 af0, af1;
    af0[0] = (short)f2bf(x0.x); af0[1] = (short)f2bf(x0.y);
    af0[2] = (short)f2bf(x0.z); af0[3] = (short)f2bf(x0.w);
    af0[4] = (short)f2bf(x1.x); af0[5] = (short)f2bf(x1.y);
    af0[6] = (short)f2bf(x1.z); af0[7] = (short)f2bf(x1.w);
    af1[0] = (short)f2bf(x2.x); af1[1] = (short)f2bf(x2.y);
    af1[2] = (short)f2bf(x2.z); af1[3] = (short)f2bf(x2.w);
    af1[4] = (short)f2bf(x3.x); af1[5] = (short)f2bf(x3.y);
    af1[6] = (short)f2bf(x3.z); af1[7] = (short)f2bf(x3.w);
    if (mat == 0) {
      // acc[nt][r] = out[token = t0+quad*4+r][d = nt*16+l16]
      f32x4 acc[4];
      #pragma unroll
      for (int nt = 0; nt < 4; ++nt) {
        acc[nt] = MFMA32(af0, wf[nt][0], z);
        acc[nt] = MFMA32(af1, wf[nt][1], acc[nt]);
      }
      // transposed store: rows d = nt*16+l16, 4 consecutive tokens as ushort4
      #pragma unroll
      for (int nt = 0; nt < 4; ++nt) {
        ushort4 o;
        o.x = f2bf(acc[nt][0]); o.y = f2bf(acc[nt][1]);
        o.z = f2bf(acc[nt][2]); o.w = f2bf(acc[nt][3]);
        size_t idx = ((size_t)((ns*HH + h)*DD + nt*16 + l16))*LL + tt*16 + quad*4;
        *(ushort4*)&vpT[idx] = o;
      }
    } else {
      // swapped: acc[nt][r] = out[token = t0+l16][d = nt*16+quad*4+r]
      f32x4 acc[4];
      #pragma unroll
      for (int nt = 0; nt < 4; ++nt) {
        acc[nt] = MFMA32(wf[nt][0], af0, z);
        acc[nt] = MFMA32(wf[nt][1], af1, acc[nt]);
      }
      #pragma unroll
      for (int nt = 0; nt < 4; ++nt) {
        ushort4 o;
        o.x = f2bf(acc[nt][0] * sc); o.y = f2bf(acc[nt][1] * sc);
        o.z = f2bf(acc[nt][2] * sc); o.w = f2bf(acc[nt][3] * sc);
        *(ushort4*)&dst[(size_t)(t0 + l16)*EE + h*DD + nt*16 + quad*4] = o;
      }
    }
    x0 = y0; x1 = y1; x2 = y2; x3 = y3;
    if (j < 2) { y0 = n0; y1 = n1; y2 = n2; y3 = n3; }
  }
}

// ---------------- K2: fused column-softmax + attention-out ----------------
// one block per (ns,h): 256 blocks x 1024 threads. K resident in LDS; V chunk
// double-buffered; P via per-wave LDS transpose; MFMA32 only.
// softmax is over the QUERY axis: colsum_l = sum_q mask_q * exp2(e_ql).
// s_setprio(1) around MFMA clusters (T5): the 16 waves are phase-staggered
// (V-stagers vs pure-compute), so priority arbitration has a role-split.
__global__ void __launch_bounds__(1024, 4) attn_kernel(
    const u16* __restrict__ qp, const u16* __restrict__ kp,
    const u16* __restrict__ vpT, const int* __restrict__ mask,
    u16* __restrict__ oat) {
  const int b = blockIdx.x;
  const int h = b & 15, ns = b >> 4;
  const int tid = threadIdx.x;
  const int wid = tid >> 6, lane = tid & 63, quad = lane >> 4, l16 = lane & 15;
  __shared__ u16 Ks[LL][72];        // K[l][d]      73728 B
  __shared__ u16 Vt[2][DD][72];     // V^T[d][l64]  18432 B
  __shared__ u16 pt[16][32][40];    // per-wave P   40960 B (phase A: psum f32[16][512])
  __shared__ float csum[LL];        //               2048 B   => 135168 B total
  float* psum = (float*)pt;
  // ---- stage K ----
  const size_t kgbase = ((size_t)(ns*LL))*EE + h*DD;
  for (int i = tid; i < 4096; i += 1024) {          // 512 rows x 8 segs of 16B
    int row = i >> 3, seg = (i & 7) * 8;
    *(bf16x8*)&Ks[row][seg] = *(const bf16x8*)&kp[kgbase + (size_t)row*EE + seg];
  }
  // ---- persistent Q fragments (wave owns 32 q rows) + masks ----
  const int q0 = wid*32;
  bf16x8 qf[2][2];
  float maf[2][4];
  #pragma unroll
  for (int qt = 0; qt < 2; ++qt) {
    const u16* qrow = qp + ((size_t)(ns*LL + q0 + qt*16 + l16))*EE + h*DD;
    qf[qt][0] = *(const bf16x8*)&qrow[quad*8];
    qf[qt][1] = *(const bf16x8*)&qrow[32 + quad*8];
    #pragma unroll
    for (int r = 0; r < 4; ++r)
      maf[qt][r] = mask[ns*LL + q0 + qt*16 + quad*4 + r] ? 1.f : 0.f;
  }
  f32x4 z = {0.f, 0.f, 0.f, 0.f};
  __syncthreads();
  // ---- phase A: column partial sums -> psum[wid][l], then block reduce ----
  for (int lt = 0; lt < 32; ++lt) {
    bf16x8 kf0 = *(const bf16x8*)&Ks[lt*16 + l16][quad*8];
    bf16x8 kf1 = *(const bf16x8*)&Ks[lt*16 + l16][32 + quad*8];
    float part = 0.f;
    #pragma unroll
    for (int qt = 0; qt < 2; ++qt) {
      __builtin_amdgcn_s_setprio(1);
      f32x4 e = MFMA32(qf[qt][0], kf0, z);
      e = MFMA32(qf[qt][1], kf1, e);
      __builtin_amdgcn_s_setprio(0);
      #pragma unroll
      for (int r = 0; r < 4; ++r)
        part += maf[qt][r] * FEXP2(e[r]);     // e row = q(quad*4+r), col = l(l16)
    }
    part += __shfl_xor(part, 16);             // combine 4 quads (same l16)
    part += __shfl_xor(part, 32);
    if (quad == 0) psum[wid*512 + lt*16 + l16] = part;
  }
  __syncthreads();
  if (tid < LL) {
    float s = 0.f;
    #pragma unroll
    for (int w = 0; w < 16; ++w) s += psum[w*512 + tid];
    csum[tid] = (s > 0.f) ? 1.f/s : 0.f;
  }
  __syncthreads();
  // ---- phase B: E recompute -> P (LDS transpose) -> PV, V chunks of 64 l ----
  f32x4 acc[4][2] = {{z,z},{z,z},{z,z},{z,z}};   // [dtile][qt]
  const size_t vgbase = ((size_t)((ns*HH + h)*DD))*LL;
  for (int lc = 0; lc < 8; ++lc) {               // 8 chunks of 64 l
    if (tid < 512) {                             // stage V^T[d][lc*64..+63]
      int row = tid >> 3, seg = (tid & 7) * 8;
      *(bf16x8*)&Vt[lc & 1][row][seg] =
          *(const bf16x8*)&vpT[vgbase + (size_t)row*LL + lc*64 + seg];
    }
    __syncthreads();                             // one barrier per chunk (dbuf)
    // E + P for 64 l in 4 sub-tiles of 16
    #pragma unroll
    for (int lt2 = 0; lt2 < 4; ++lt2) {
      const int lrow = lc*64 + lt2*16 + l16;
      bf16x8 kf0 = *(const bf16x8*)&Ks[lrow][quad*8];
      bf16x8 kf1 = *(const bf16x8*)&Ks[lrow][32 + quad*8];
      const float csv = csum[lrow];
      #pragma unroll
      for (int qt = 0; qt < 2; ++qt) {
        __builtin_amdgcn_s_setprio(1);
        f32x4 e = MFMA32(qf[qt][0], kf0, z);
        e = MFMA32(qf[qt][1], kf1, e);
        __builtin_amdgcn_s_setprio(0);
        #pragma unroll
        for (int r = 0; r < 4; ++r)
          pt[wid][qt*16 + quad*4 + r][lt2 & 1 ? 16 + l16 : l16] =
              f2bf(maf[qt][r] * csv * FEXP2(e[r]));
        // PV for the 32-l half once both sub-tiles of it are in pt
        if (lt2 & 1) {
          bf16x8 pa = *(const bf16x8*)&pt[wid][qt*16 + l16][quad*8];
          __builtin_amdgcn_s_setprio(1);
          #pragma unroll
          for (int dt = 0; dt < 4; ++dt) {
            bf16x8 vb = *(const bf16x8*)&Vt[lc & 1][dt*16 + l16]
                                        [(lt2 >> 1)*32 + quad*8];
            acc[dt][qt] = MFMA32(pa, vb, acc[dt][qt]);
          }
          __builtin_amdgcn_s_setprio(0);
        }
      }
    }
  }
  // ---- write out[q][d]: D row = q(quad*4+r), col = d(l16) ----
  #pragma unroll
  for (int qt = 0; qt < 2; ++qt)
    #pragma unroll
    for (int dt = 0; dt < 4; ++dt)
      #pragma unroll
      for (int r = 0; r < 4; ++r)
        oat[((size_t)(ns*LL + q0 + qt*16 + quad*4 + r))*EE + h*DD + dt*16 + l16] =
            f2bf(acc[dt][qt][r]);
}

// ---------------- K4: Y = oat @ Wo^T + bo, m97-style MFMA GEMM --------------
// 128x128 tile, BK=64, 4 waves each computing a 64x64 quadrant. Staging via
// global_load_lds width=16 into linear (unpadded) LDS.
__global__ void __launch_bounds__(256) out_gemm_kernel(
    const u16* __restrict__ A, const u16* __restrict__ Wob,
    const float* __restrict__ bo, float* __restrict__ Y) {
  __shared__ u16 As[128][64];   // [m][k]  16384 B, linear for global_load_lds
  __shared__ u16 Bs[128][64];   // [n][k]  16384 B
  const int b = blockIdx.x;     // 64 mtiles x 8 ntiles
  const int nb = b & 7, mb = b >> 3;
  const int m0 = mb*128, n0 = nb*128;
  const int tid = threadIdx.x;
  const int wid = tid >> 6, lane = tid & 63, quad = lane >> 4, l16 = lane & 15;
  const int wm = (wid >> 1)*64, wn = (wid & 1)*64;   // wave quadrant
  const int r0 = tid >> 3, sseg = (tid & 7) * 8;     // staging row/col (u16)
  u16* adst = &As[0][0] + tid*8;                     // lane-linear 16B chunks
  u16* bdst = &Bs[0][0] + tid*8;
  f32x4 z = {0.f, 0.f, 0.f, 0.f};
  f32x4 acc[4][4];
  #pragma unroll
  for (int i = 0; i < 4; ++i)
    #pragma unroll
    for (int j = 0; j < 4; ++j) acc[i][j] = z;
  for (int k0 = 0; k0 < EE; k0 += 64) {
    __syncthreads();                    // previous tile fully consumed
    #pragma unroll
    for (int it = 0; it < 4; ++it) {    // 128 rows x 64 k each, 16B/lane/issue
      gload16(&A  [(size_t)(m0 + it*32 + r0)*EE + k0 + sseg], adst + it*2048);
      gload16(&Wob[(size_t)(n0 + it*32 + r0)*EE + k0 + sseg], bdst + it*2048);
    }
    __syncthreads();                    // vmcnt(0) drain -> LDS data ready
    #pragma unroll
    for (int kk = 0; kk < 2; ++kk) {
      bf16x8 af[4], bfr[4];
      #pragma unroll
      for (int i = 0; i < 4; ++i)
        af[i] = *(const bf16x8*)&As[wm + i*16 + l16][kk*32 + quad*8];
      #pragma unroll
      for (int j = 0; j < 4; ++j)
        bfr[j] = *(const bf16x8*)&Bs[wn + j*16 + l16][kk*32 + quad*8];
      #pragma unroll
      for (int i = 0; i < 4; ++i)
        #pragma unroll
        for (int j = 0; j < 4; ++j)
          acc[i][j] = MFMA32(af[i], bfr[j], acc[i][j]);
    }
  }
  #pragma unroll
  for (int i = 0; i < 4; ++i)
    #pragma unroll
    for (int j = 0; j < 4; ++j) {
      int col = n0 + wn + j*16 + l16;
      float bias = bo[col];
      #pragma unroll
      for (int r = 0; r < 4; ++r)
        Y[(size_t)(m0 + wm + i*16 + quad*4 + r)*EE + col] = acc[i][j][r] + bias;
    }
}

extern "C" void kernel_launch(void* const* d_in, const int* in_sizes, int n_in,
                              void* d_out, int out_size, void* d_ws, size_t ws_size,
                              hipStream_t stream) {
  const float* values = (const float*)d_in[0];
  const float* keysp  = (const float*)d_in[1];
  const float* query  = (const float*)d_in[2];
  const int*   mask   = (const int*)d_in[3];
  const float* Wv = (const float*)d_in[4];
  const float* Wk = (const float*)d_in[5];
  const float* Wq = (const float*)d_in[6];
  const float* Wo = (const float*)d_in[7];
  const float* bo = (const float*)d_in[8];
  float* Y = (float*)d_out;

  u16* qp  = (u16*)d_ws;
  u16* kp  = qp + NSLE;
  u16* vpT = kp + NSLE;
  u16* oat = vpT + NSLE;
  u16* Wob = oat + NSLE;
  u16* Wvb = Wob + EE*EE;
  u16* Wkb = Wvb + DD*DD;
  u16* Wqb = Wkb + DD*DD;

  convw_kernel<<<1036, 256, 0, stream>>>(Wv, Wk, Wq, Wo, Wvb, Wkb, Wqb, Wob);
  proj_kernel<<<3*NSX*4*8, 256, 0, stream>>>(values, keysp, query,
                                             Wvb, Wkb, Wqb, vpT, kp, qp);
  attn_kernel<<<NSX*HH, 1024, 0, stream>>>(qp, kp, vpT, mask, oat);
  out_gemm_kernel<<<(NT/128)*(EE/128), 256, 0, stream>>>(oat, Wob, bo, Y);
}

// Round 3
// 230.695 us; speedup vs baseline: 1.0410x; 1.0093x over previous
//
#include <hip/hip_runtime.h>
#include <math.h>

#define LL 512
#define EE 1024
#define HH 16
#define DD 64
#define NSX 16               // N*S
#define NT (NSX*LL)          // 8192 tokens
#define NSLE (NT*EE)         // 8388608
// q is pre-scaled by (1/sqrt(512)) * log2(e) so softmax uses native exp2
#define SCALE_Q 0.06375871f

typedef unsigned short u16;
typedef short bf16x8 __attribute__((ext_vector_type(8)));
typedef float f32x4 __attribute__((ext_vector_type(4)));

__device__ inline u16 f2bf(float f) {
  unsigned u = __float_as_uint(f);
  u += 0x7fff + ((u >> 16) & 1);          // RNE
  return (u16)(u >> 16);
}

// direct builtin calls only; ONLY gfx950-verified MFMA shapes (16x16x32)
#define FEXP2(x) __builtin_amdgcn_exp2f(x)
#define MFMA32(a, b, c) __builtin_amdgcn_mfma_f32_16x16x32_bf16((a), (b), (c), 0, 0, 0)

// async 16B global->LDS (wave-uniform LDS base + lane*16 layout)
__device__ inline void gload16(const void* g, void* l) {
  __builtin_amdgcn_global_load_lds(
      (const __attribute__((address_space(1))) unsigned int*)g,
      (__attribute__((address_space(3))) unsigned int*)l, 16, 0, 0);
}

// ---------------- K0: convert weights fp32 -> bf16 ----------------
__global__ void __launch_bounds__(256) convw_kernel(
    const float* __restrict__ Wv, const float* __restrict__ Wk,
    const float* __restrict__ Wq, const float* __restrict__ Wo,
    u16* __restrict__ Wvb, u16* __restrict__ Wkb,
    u16* __restrict__ Wqb, u16* __restrict__ Wob) {
  int i = blockIdx.x * 256 + threadIdx.x;   // quad index
  const float* s; u16* d; int j;
  if (i < 262144) { s = Wo; d = Wob; j = i; }
  else {
    j = i - 262144;
    if (j < 1024)      { s = Wv; d = Wvb; }
    else if (j < 2048) { s = Wk; d = Wkb; j -= 1024; }
    else               { s = Wq; d = Wqb; j -= 2048; }
  }
  float4 f = ((const float4*)s)[j];
  ushort4 o; o.x = f2bf(f.x); o.y = f2bf(f.y); o.z = f2bf(f.z); o.w = f2bf(f.w);
  ((ushort4*)d)[j] = o;
}

// ---------------- K1: projections via MFMA, LDS-free, 2-deep pipelined ------
// grid = mat(3) x ns(16) x hg(4) x tt0(8) = 1536 blocks; wave = one head; each
// wave processes 4 token-tiles (tt = tt0 + 8j) with loads for tiles j+1 AND
// j+2 in flight while computing tile j (8 x 16B outstanding).
// v stored transposed vpT[ns][h][d][l] via MFMA(af,wf); k/q stored row-major
// via SWAPPED MFMA(wf,af) (verified r1/r2) so the epilogue is 4 ushort4 stores.
__global__ void __launch_bounds__(256) proj_kernel(
    const float* __restrict__ vals, const float* __restrict__ keys,
    const float* __restrict__ qry,
    const u16* __restrict__ Wvb, const u16* __restrict__ Wkb,
    const u16* __restrict__ Wqb,
    u16* __restrict__ vpT, u16* __restrict__ kp, u16* __restrict__ qp) {
  const int b = blockIdx.x;
  const int tt0 = b & 7, hg = (b >> 3) & 3, ns = (b >> 5) & 15, mat = b >> 9;
  const int tid = threadIdx.x;
  const int wid = tid >> 6, lane = tid & 63, quad = lane >> 4, l16 = lane & 15;
  const int h = hg*4 + wid;
  const float* src = (mat == 0 ? vals : mat == 1 ? keys : qry);
  const u16*   W   = (mat == 0 ? Wvb  : mat == 1 ? Wkb  : Wqb);
  u16* dst = (mat == 1 ? kp : qp);
  const float sc = (mat == 2) ? SCALE_Q : 1.f;
  // ---- W fragments: loaded once, register-resident across all 4 tiles ----
  bf16x8 wf[4][2];
  #pragma unroll
  for (int nt = 0; nt < 4; ++nt) {
    wf[nt][0] = *(const bf16x8*)&W[(nt*16 + l16)*DD + quad*8];
    wf[nt][1] = *(const bf16x8*)&W[(nt*16 + l16)*DD + 32 + quad*8];
  }
  f32x4 z = {0.f, 0.f, 0.f, 0.f};
  // ---- prologue: loads for tiles j=0 and j=1 ----
  const float* xr0 = src + (size_t)(ns*LL + tt0*16 + l16)*EE + h*DD;
  const float* xr1 = xr0 + (size_t)128*EE;             // +8 token-tiles
  float4 x0 = *(const float4*)&xr0[quad*8];
  float4 x1 = *(const float4*)&xr0[quad*8 + 4];
  float4 x2 = *(const float4*)&xr0[32 + quad*8];
  float4 x3 = *(const float4*)&xr0[32 + quad*8 + 4];
  float4 y0 = *(const float4*)&xr1[quad*8];
  float4 y1 = *(const float4*)&xr1[quad*8 + 4];
  float4 y2 = *(const float4*)&xr1[32 + quad*8];
  float4 y3 = *(const float4*)&xr1[32 + quad*8 + 4];
  #pragma unroll
  for (int j = 0; j < 4; ++j) {
    const int tt = tt0 + 8*j;
    const int t0 = ns*LL + tt*16;
    // ---- issue loads for tile j+2 before touching this tile's data ----
    float4 n0, n1, n2, n3;
    if (j < 2) {
      const float* xrn = src + (size_t)(t0 + 256 + l16)*EE + h*DD;  // +16 tiles
      n0 = *(const float4*)&xrn[quad*8];
      n1 = *(const float4*)&xrn[quad*8 + 4];
      n2 = *(const float4*)&xrn[32 + quad*8];
      n3 = *(const float4*)&xrn[32 + quad*8 + 4];
    }
    // ---- convert current tile ----
    bf16x8 af0, af1;
    af0[0] = (short)f2bf(x0.x); af0[1] = (short)f2bf(x0.y);
    af0[2] = (short)f2bf(x0.z); af0[3] = (short)f2bf(x0.w);
    af0[4] = (short)f2bf(x1.x); af0[5] = (short)f2bf(x1.y);
    af0[6] = (short)f2bf(x1.z); af0[7] = (short)f2bf(x1.w);
    af1[0] = (short)f2bf(x2.x); af1[1] = (short)f2bf(x2.y);
    af1[2] = (short)f2bf(x2.z); af1[3] = (short)f2bf(x2.w);
    af1[4] = (short)f2bf(x3.x); af1[5] = (short)f2bf(x3.y);
    af1[6] = (short)f2bf(x3.z); af1[7] = (short)f2bf(x3.w);
    if (mat == 0) {
      // acc[nt][r] = out[token = t0+quad*4+r][d = nt*16+l16]
      f32x4 acc[4];
      #pragma unroll
      for (int nt = 0; nt < 4; ++nt) {
        acc[nt] = MFMA32(af0, wf[nt][0], z);
        acc[nt] = MFMA32(af1, wf[nt][1], acc[nt]);
      }
      // transposed store: rows d = nt*16+l16, 4 consecutive tokens as ushort4
      #pragma unroll
      for (int nt = 0; nt < 4; ++nt) {
        ushort4 o;
        o.x = f2bf(acc[nt][0]); o.y = f2bf(acc[nt][1]);
        o.z = f2bf(acc[nt][2]); o.w = f2bf(acc[nt][3]);
        size_t idx = ((size_t)((ns*HH + h)*DD + nt*16 + l16))*LL + tt*16 + quad*4;
        *(ushort4*)&vpT[idx] = o;
      }
    } else {
      // swapped: acc[nt][r] = out[token = t0+l16][d = nt*16+quad*4+r]
      f32x4 acc[4];
      #pragma unroll
      for (int nt = 0; nt < 4; ++nt) {
        acc[nt] = MFMA32(wf[nt][0], af0, z);
        acc[nt] = MFMA32(wf[nt][1], af1, acc[nt]);
      }
      #pragma unroll
      for (int nt = 0; nt < 4; ++nt) {
        ushort4 o;
        o.x = f2bf(acc[nt][0] * sc); o.y = f2bf(acc[nt][1] * sc);
        o.z = f2bf(acc[nt][2] * sc); o.w = f2bf(acc[nt][3] * sc);
        *(ushort4*)&dst[(size_t)(t0 + l16)*EE + h*DD + nt*16 + quad*4] = o;
      }
    }
    x0 = y0; x1 = y1; x2 = y2; x3 = y3;
    if (j < 2) { y0 = n0; y1 = n1; y2 = n2; y3 = n3; }
  }
}

// ---------------- K2: fused column-softmax + attention-out ----------------
// one block per (ns,h): 256 blocks x 1024 threads. K resident in LDS; V chunk
// double-buffered. softmax is over the QUERY axis: csum_l = sum_q m_q*exp2(e).
// Phase B uses SWAPPED QK^T (E^T = MFMA(K,Q), layout verified r1) so each lane
// holds 4 l-values of one q-column -> P written to pt as ONE ushort4 per
// (tile,qt) (8 vectored writes/chunk, ~2-way banks) instead of 32 scalar b16
// at 4-way. pt consume side (pa b128, A-operand rows=q) identical to r0.
// No setprio (measured -5% in r2).
__global__ void __launch_bounds__(1024, 4) attn_kernel(
    const u16* __restrict__ qp, const u16* __restrict__ kp,
    const u16* __restrict__ vpT, const int* __restrict__ mask,
    u16* __restrict__ oat) {
  const int b = blockIdx.x;
  const int h = b & 15, ns = b >> 4;
  const int tid = threadIdx.x;
  const int wid = tid >> 6, lane = tid & 63, quad = lane >> 4, l16 = lane & 15;
  __shared__ u16 Ks[LL][72];        // K[l][d]      73728 B
  __shared__ u16 Vt[2][DD][72];     // V^T[d][l64]  18432 B
  __shared__ u16 pt[16][32][40];    // per-wave P   40960 B (phase A: psum f32[16][512])
  __shared__ float csum[LL];        //               2048 B   => 135168 B total
  float* psum = (float*)pt;
  // ---- stage K ----
  const size_t kgbase = ((size_t)(ns*LL))*EE + h*DD;
  for (int i = tid; i < 4096; i += 1024) {          // 512 rows x 8 segs of 16B
    int row = i >> 3, seg = (i & 7) * 8;
    *(bf16x8*)&Ks[row][seg] = *(const bf16x8*)&kp[kgbase + (size_t)row*EE + seg];
  }
  // ---- persistent Q fragments (wave owns 32 q rows) + masks ----
  const int q0 = wid*32;
  bf16x8 qf[2][2];
  float maf[2][4];    // phase A: q = q0+qt*16+quad*4+r
  float mqf[2];       // phase B: q = q0+qt*16+l16
  #pragma unroll
  for (int qt = 0; qt < 2; ++qt) {
    const u16* qrow = qp + ((size_t)(ns*LL + q0 + qt*16 + l16))*EE + h*DD;
    qf[qt][0] = *(const bf16x8*)&qrow[quad*8];
    qf[qt][1] = *(const bf16x8*)&qrow[32 + quad*8];
    #pragma unroll
    for (int r = 0; r < 4; ++r)
      maf[qt][r] = mask[ns*LL + q0 + qt*16 + quad*4 + r] ? 1.f : 0.f;
    mqf[qt] = mask[ns*LL + q0 + qt*16 + l16] ? 1.f : 0.f;
  }
  f32x4 z = {0.f, 0.f, 0.f, 0.f};
  __syncthreads();
  // ---- phase A: column partial sums -> psum[wid][l], then block reduce ----
  for (int lt = 0; lt < 32; ++lt) {
    bf16x8 kf0 = *(const bf16x8*)&Ks[lt*16 + l16][quad*8];
    bf16x8 kf1 = *(const bf16x8*)&Ks[lt*16 + l16][32 + quad*8];
    float part = 0.f;
    #pragma unroll
    for (int qt = 0; qt < 2; ++qt) {
      f32x4 e = MFMA32(qf[qt][0], kf0, z);
      e = MFMA32(qf[qt][1], kf1, e);
      #pragma unroll
      for (int r = 0; r < 4; ++r)
        part += maf[qt][r] * FEXP2(e[r]);     // e row = q(quad*4+r), col = l(l16)
    }
    part += __shfl_xor(part, 16);             // combine 4 quads (same l16)
    part += __shfl_xor(part, 32);
    if (quad == 0) psum[wid*512 + lt*16 + l16] = part;
  }
  __syncthreads();
  if (tid < LL) {
    float s = 0.f;
    #pragma unroll
    for (int w = 0; w < 16; ++w) s += psum[w*512 + tid];
    csum[tid] = (s > 0.f) ? 1.f/s : 0.f;
  }
  __syncthreads();
  // ---- phase B: E^T recompute -> P via ushort4 -> PV, V chunks of 64 l ----
  f32x4 acc[4][2] = {{z,z},{z,z},{z,z},{z,z}};   // [dtile][qt]
  const size_t vgbase = ((size_t)((ns*HH + h)*DD))*LL;
  for (int lc = 0; lc < 8; ++lc) {               // 8 chunks of 64 l
    if (tid < 512) {                             // stage V^T[d][lc*64..+63]
      int row = tid >> 3, seg = (tid & 7) * 8;
      *(bf16x8*)&Vt[lc & 1][row][seg] =
          *(const bf16x8*)&vpT[vgbase + (size_t)row*LL + lc*64 + seg];
    }
    __syncthreads();                             // one barrier per chunk (dbuf)
    // E^T + P for 64 l in 4 sub-tiles of 16
    #pragma unroll
    for (int lt2 = 0; lt2 < 4; ++lt2) {
      const int lb = lc*64 + lt2*16;
      bf16x8 kf0 = *(const bf16x8*)&Ks[lb + l16][quad*8];
      bf16x8 kf1 = *(const bf16x8*)&Ks[lb + l16][32 + quad*8];
      float4 cs4 = *(const float4*)&csum[lb + quad*4];   // csum for l=lb+quad*4+r
      #pragma unroll
      for (int qt = 0; qt < 2; ++qt) {
        // E^T: lane holds e[l = lb+quad*4+r][q = q0+qt*16+l16]
        f32x4 e = MFMA32(kf0, qf[qt][0], z);
        e = MFMA32(kf1, qf[qt][1], e);
        const float m = mqf[qt];
        ushort4 o;
        o.x = f2bf(m * cs4.x * FEXP2(e[0]));
        o.y = f2bf(m * cs4.y * FEXP2(e[1]));
        o.z = f2bf(m * cs4.z * FEXP2(e[2]));
        o.w = f2bf(m * cs4.w * FEXP2(e[3]));
        // P[q][l]: row q = qt*16+l16, cols l-rel = (lt2&1)*16 + quad*4 .. +3
        *(ushort4*)&pt[wid][qt*16 + l16][(lt2 & 1)*16 + quad*4] = o;
        // PV for the 32-l half once both sub-tiles of it are in pt
        if (lt2 & 1) {
          bf16x8 pa = *(const bf16x8*)&pt[wid][qt*16 + l16][quad*8];
          #pragma unroll
          for (int dt = 0; dt < 4; ++dt) {
            bf16x8 vb = *(const bf16x8*)&Vt[lc & 1][dt*16 + l16]
                                        [(lt2 >> 1)*32 + quad*8];
            acc[dt][qt] = MFMA32(pa, vb, acc[dt][qt]);
          }
        }
      }
    }
  }
  // ---- write out[q][d]: D row = q(quad*4+r), col = d(l16) ----
  #pragma unroll
  for (int qt = 0; qt < 2; ++qt)
    #pragma unroll
    for (int dt = 0; dt < 4; ++dt)
      #pragma unroll
      for (int r = 0; r < 4; ++r)
        oat[((size_t)(ns*LL + q0 + qt*16 + quad*4 + r))*EE + h*DD + dt*16 + l16] =
            f2bf(acc[dt][qt][r]);
}

// ---------------- K4: Y = oat @ Wo^T + bo, m97-style MFMA GEMM --------------
// 128x64 tile, BK=64 -> grid 1024 = 4 blocks/CU (was 512 = 2/CU: block-count
// limited). 4 waves as 2x2 over (128m x 64n), each computing 64x32.
// Staging via global_load_lds width=16 into linear LDS.
__global__ void __launch_bounds__(256) out_gemm_kernel(
    const u16* __restrict__ A, const u16* __restrict__ Wob,
    const float* __restrict__ bo, float* __restrict__ Y) {
  __shared__ u16 As[128][64];   // [m][k]  16384 B, linear for global_load_lds
  __shared__ u16 Bs[64][64];    // [n][k]   8192 B
  const int b = blockIdx.x;     // 64 mtiles x 16 ntiles
  const int nb = b & 15, mb = b >> 4;
  const int m0 = mb*128, n0 = nb*64;
  const int tid = threadIdx.x;
  const int wid = tid >> 6, lane = tid & 63, quad = lane >> 4, l16 = lane & 15;
  const int wm = (wid >> 1)*64, wn = (wid & 1)*32;   // wave sub-tile 64x32
  const int r0 = tid >> 3, sseg = (tid & 7) * 8;     // staging row/col (u16)
  u16* adst = &As[0][0] + tid*8;                     // lane-linear 16B chunks
  u16* bdst = &Bs[0][0] + tid*8;
  f32x4 z = {0.f, 0.f, 0.f, 0.f};
  f32x4 acc[4][2];
  #pragma unroll
  for (int i = 0; i < 4; ++i)
    #pragma unroll
    for (int j = 0; j < 2; ++j) acc[i][j] = z;
  for (int k0 = 0; k0 < EE; k0 += 64) {
    __syncthreads();                    // previous tile fully consumed
    #pragma unroll
    for (int it = 0; it < 4; ++it)      // A: 128 rows x 64 k
      gload16(&A[(size_t)(m0 + it*32 + r0)*EE + k0 + sseg], adst + it*2048);
    #pragma unroll
    for (int it = 0; it < 2; ++it)      // B: 64 rows x 64 k
      gload16(&Wob[(size_t)(n0 + it*32 + r0)*EE + k0 + sseg], bdst + it*2048);
    __syncthreads();                    // vmcnt(0) drain -> LDS data ready
    #pragma unroll
    for (int kk = 0; kk < 2; ++kk) {
      bf16x8 af[4], bfr[2];
      #pragma unroll
      for (int i = 0; i < 4; ++i)
        af[i] = *(const bf16x8*)&As[wm + i*16 + l16][kk*32 + quad*8];
      #pragma unroll
      for (int j = 0; j < 2; ++j)
        bfr[j] = *(const bf16x8*)&Bs[wn + j*16 + l16][kk*32 + quad*8];
      #pragma unroll
      for (int i = 0; i < 4; ++i)
        #pragma unroll
        for (int j = 0; j < 2; ++j)
          acc[i][j] = MFMA32(af[i], bfr[j], acc[i][j]);
    }
  }
  #pragma unroll
  for (int i = 0; i < 4; ++i)
    #pragma unroll
    for (int j = 0; j < 2; ++j) {
      int col = n0 + wn + j*16 + l16;
      float bias = bo[col];
      #pragma unroll
      for (int r = 0; r < 4; ++r)
        Y[(size_t)(m0 + wm + i*16 + quad*4 + r)*EE + col] = acc[i][j][r] + bias;
    }
}

extern "C" void kernel_launch(void* const* d_in, const int* in_sizes, int n_in,
                              void* d_out, int out_size, void* d_ws, size_t ws_size,
                              hipStream_t stream) {
  const float* values = (const float*)d_in[0];
  const float* keysp  = (const float*)d_in[1];
  const float* query  = (const float*)d_in[2];
  const int*   mask   = (const int*)d_in[3];
  const float* Wv = (const float*)d_in[4];
  const float* Wk = (const float*)d_in[5];
  const float* Wq = (const float*)d_in[6];
  const float* Wo = (const float*)d_in[7];
  const float* bo = (const float*)d_in[8];
  float* Y = (float*)d_out;

  u16* qp  = (u16*)d_ws;
  u16* kp  = qp + NSLE;
  u16* vpT = kp + NSLE;
  u16* oat = vpT + NSLE;
  u16* Wob = oat + NSLE;
  u16* Wvb = Wob + EE*EE;
  u16* Wkb = Wvb + DD*DD;
  u16* Wqb = Wkb + DD*DD;

  convw_kernel<<<1036, 256, 0, stream>>>(Wv, Wk, Wq, Wo, Wvb, Wkb, Wqb, Wob);
  proj_kernel<<<3*NSX*4*8, 256, 0, stream>>>(values, keysp, query,
                                             Wvb, Wkb, Wqb, vpT, kp, qp);
  attn_kernel<<<NSX*HH, 1024, 0, stream>>>(qp, kp, vpT, mask, oat);
  out_gemm_kernel<<<(NT/128)*(EE/64), 256, 0, stream>>>(oat, Wob, bo, Y);
}